// Round 33
// baseline (244.950 us; speedup 1.0000x reference)
//
#include <hip/hip_runtime.h>
#include <math.h>

#define NN 16384
#define NRB 32
#define EE 262144
#define TEB 64          // edges per tile (4 waves x 16)
#define TPB_E 16        // tiles per block (software pipeline)

typedef __attribute__((ext_vector_type(8))) short short8v;   // 8 bf16
typedef __attribute__((ext_vector_type(4))) float f32x4;

__device__ __forceinline__ float silu_f(float x) {
    return x * __builtin_amdgcn_rcpf(1.0f + __expf(-x));
}
__device__ __forceinline__ int degmap(int j) { return (j == 0) ? 0 : (j < 4) ? 1 : (j < 9) ? 2 : 3; }
__device__ __forceinline__ unsigned short f2b(float f) {          // RNE (prep path)
    unsigned int u = __float_as_uint(f);
    unsigned int r = (u + 0x7FFFu + ((u >> 16) & 1u)) >> 16;
    return (unsigned short)r;
}
__device__ __forceinline__ unsigned short f2bt(float f) {         // truncate (hot path)
    return (unsigned short)(__float_as_uint(f) >> 16);
}
__device__ __forceinline__ float b2f(short s) {
    return __uint_as_float(((unsigned int)(unsigned short)s) << 16);
}

// ---------------------------------------------------------------------------
// FUSED dispatch 1: prep_weights (blocks 0..191) + csr_count (blocks 192..1215)
// ---------------------------------------------------------------------------
__global__ __launch_bounds__(256) void fused_prep(
    const float* __restrict__ fi_w1r, const float* __restrict__ fi_w2r,
    const float* __restrict__ fi_w2e,
    const float* __restrict__ fe_w1r, const float* __restrict__ fe_w2r,
    const float* __restrict__ fe_w2e,
    unsigned short* __restrict__ wbf,
    const int* __restrict__ recv,
    int* __restrict__ cnt)
{
    const int tid = threadIdx.x;
    if (blockIdx.x < 192) {
        const int id = blockIdx.x * 256 + tid;   // 49152 total
        if (id >= 2 * 24576) return;
        const int p = id / 24576;
        const int r = id % 24576;
        const float* w1r = p ? fe_w1r : fi_w1r;
        const float* w2r = p ? fe_w2r : fi_w2r;
        const float* w2e = p ? fe_w2e : fi_w2e;
        float v;
        if (r < 4096) {               // w1rT: c = r>>5, k = r&31
            v = w1r[(r & 31) * 128 + (r >> 5)];
        } else if (r < 20480) {       // w2rT: c = rr>>7, k = rr&127
            const int rr = r - 4096;
            v = w2r[(rr & 127) * 128 + (rr >> 7)];
        } else {                      // w2eT: c = rr>>5, k = rr&31
            const int rr = r - 20480;
            v = w2e[(rr & 31) * 128 + (rr >> 5)];
        }
        wbf[p * 24576 + r] = f2b(v);
    } else {
        const int e = (blockIdx.x - 192) * 256 + tid;
        if (e < EE) atomicAdd(&cnt[recv[e]], 1);
    }
}

// ---------------------------------------------------------------------------
// csr_scan (single block)
// ---------------------------------------------------------------------------
__global__ __launch_bounds__(256) void csr_scan(const int* __restrict__ cnt,
                                                int* __restrict__ off) {
    __shared__ int ps[256];
    const int t = threadIdx.x;
    const int base = t * 64;
    int s = 0;
    for (int i = 0; i < 64; ++i) s += cnt[base + i];
    ps[t] = s;
    __syncthreads();
    for (int dd = 1; dd < 256; dd <<= 1) {
        int v = 0;
        if (t >= dd) v = ps[t - dd];
        __syncthreads();
        ps[t] += v;
        __syncthreads();
    }
    int run = ps[t] - s;  // exclusive prefix
    for (int i = 0; i < 64; ++i) {
        off[base + i] = run;
        run += cnt[base + i];
    }
}

// ---------------------------------------------------------------------------
// FUSED dispatch 3: csr_fill (blocks 0..1023) + node_proj (blocks 1024..3071).
// ---------------------------------------------------------------------------
__global__ __launch_bounds__(256) void fused_fill(
    const int* __restrict__ recv,
    const int* __restrict__ send,
    const float* __restrict__ rbf,
    const float* __restrict__ cutoffs,
    const float* __restrict__ ev_feat,
    const float* __restrict__ sh,
    const int* __restrict__ off,
    int* __restrict__ cursor,
    int* __restrict__ s_sid,
    int* __restrict__ s_rid,
    unsigned short* __restrict__ rbf_s,
    float* __restrict__ cut_s,
    float* __restrict__ evinv_s,
    unsigned short* __restrict__ sh_s,
    const float* __restrict__ inv,
    const float* __restrict__ Wq_inv, const float* __restrict__ Wk_inv,
    const float* __restrict__ Wv_inv,
    const float* __restrict__ Wq_ev, const float* __restrict__ Wk_ev,
    unsigned short* __restrict__ q_inv, unsigned short* __restrict__ k_inv,
    unsigned short* __restrict__ v_inv,
    unsigned short* __restrict__ q_ev, unsigned short* __restrict__ k_ev)
{
    const int tid = threadIdx.x;
    if (blockIdx.x < 1024) {
        // ---------------- csr_fill ----------------
        const int e = blockIdx.x * 256 + tid;
        if (e < EE) {
            const int r = recv[e];
            const int s = send[e];
            const int p = off[r] + atomicAdd(&cursor[r], 1);
            s_sid[p] = s;
            s_rid[p] = r;
            cut_s[p] = cutoffs[e];
            const float* src = rbf + (size_t)e * 32;
            unsigned short* dst = rbf_s + (size_t)p * 32;
            #pragma unroll
            for (int c = 0; c < 4; ++c) {
                const float4 a = *(const float4*)(src + c * 8);
                const float4 b = *(const float4*)(src + c * 8 + 4);
                short8v pk;
                pk[0] = f2b(a.x); pk[1] = f2b(a.y); pk[2] = f2b(a.z); pk[3] = f2b(a.w);
                pk[4] = f2b(b.x); pk[5] = f2b(b.y); pk[6] = f2b(b.z); pk[7] = f2b(b.w);
                *(short8v*)(dst + c * 8) = pk;
            }
            const float* shp = sh + (size_t)e * 16;
            unsigned short* shd = sh_s + (size_t)p * 16;
            #pragma unroll
            for (int c = 0; c < 2; ++c) {
                const float4 a = *(const float4*)(shp + c * 8);
                const float4 b = *(const float4*)(shp + c * 8 + 4);
                short8v pk;
                pk[0] = f2b(a.x); pk[1] = f2b(a.y); pk[2] = f2b(a.z); pk[3] = f2b(a.w);
                pk[4] = f2b(b.x); pk[5] = f2b(b.y); pk[6] = f2b(b.z); pk[7] = f2b(b.w);
                *(short8v*)(shd + c * 8) = pk;
            }
            const float* es = ev_feat + (size_t)s * 16;
            const float* er = ev_feat + (size_t)r * 16;
            float df[16];
            #pragma unroll
            for (int j = 0; j < 16; j += 4) {
                const float4 a = *(const float4*)(es + j);
                const float4 b = *(const float4*)(er + j);
                df[j] = a.x - b.x; df[j + 1] = a.y - b.y;
                df[j + 2] = a.z - b.z; df[j + 3] = a.w - b.w;
            }
            float4 ev4;
            ev4.x = df[0] * df[0];
            ev4.y = df[1] * df[1] + df[2] * df[2] + df[3] * df[3];
            float a2 = 0.f;
            #pragma unroll
            for (int j = 4; j < 9; ++j) a2 += df[j] * df[j];
            ev4.z = a2;
            float a3 = 0.f;
            #pragma unroll
            for (int j = 9; j < 16; ++j) a3 += df[j] * df[j];
            ev4.w = a3;
            *(float4*)(evinv_s + (size_t)p * 4) = ev4;
        }
    } else {
        // ---------------- node_proj (2 nodes/iter x 4 iters) ----------------
        const int b = blockIdx.x - 1024;       // 0..2047
        const int t = tid & 127;
        const int half = tid >> 7;
        const int h = t >> 4, e = t & 15;
        const int l = t >> 5, e2 = t & 31;

        float wq[16], wk[16], wv[16];
        #pragma unroll
        for (int d = 0; d < 16; ++d) {
            wq[d] = Wq_inv[h * 256 + d * 16 + e];
            wk[d] = Wk_inv[h * 256 + d * 16 + e];
            wv[d] = Wv_inv[h * 256 + d * 16 + e];
        }
        float wqe[32], wke[32];
        #pragma unroll
        for (int d = 0; d < 32; ++d) {
            wqe[d] = Wq_ev[l * 1024 + d * 32 + e2];
            wke[d] = Wk_ev[l * 1024 + d * 32 + e2];
        }

        __shared__ float x[256];
        for (int nn = 0; nn < 4; ++nn) {
            const int n = b * 8 + nn * 2 + half;
            __syncthreads();
            x[half * 128 + t] = inv[(size_t)n * 128 + t];
            __syncthreads();
            float aq = 0.f, ak = 0.f, av = 0.f;
            #pragma unroll
            for (int d = 0; d < 16; ++d) {
                const float xv = x[half * 128 + h * 16 + d];
                aq += xv * wq[d]; ak += xv * wk[d]; av += xv * wv[d];
            }
            q_inv[(size_t)n * 128 + t] = f2b(aq);
            k_inv[(size_t)n * 128 + t] = f2b(ak);
            v_inv[(size_t)n * 128 + t] = f2b(av);
            float bq = 0.f, bk = 0.f;
            #pragma unroll
            for (int d = 0; d < 32; ++d) {
                const float xv = x[half * 128 + l * 32 + d];
                bq += xv * wqe[d]; bk += xv * wke[d];
            }
            q_ev[(size_t)n * 128 + t] = f2b(bq);
            k_ev[(size_t)n * 128 + t] = f2b(bk);
        }
    }
}

// ---------------------------------------------------------------------------
// Kernel 2: MFMA edge kernel. r32 structure, REGISTER-SLIMMED pipeline:
//   only {sC,rC,rbC} carried across iterations; evinv/cut loaded in-loop
//   (sequential streams, issued early / used late). Target VGPR <= 168 so
//   VGPR allows 3 waves/SIMD, matching the 50,688B LDS (3 blocks/CU).
// ---------------------------------------------------------------------------
__global__ __launch_bounds__(256) void edge_kernel(
    const unsigned short* __restrict__ rbf_s,
    const float* __restrict__ cut_s,
    const float* __restrict__ evinv_s,
    const int* __restrict__ s_sid,
    const int* __restrict__ s_rid,
    const unsigned short* __restrict__ wbf,
    const float* __restrict__ fi_b1r, const float* __restrict__ fi_b2r,
    const float* __restrict__ fi_w1e, const float* __restrict__ fi_b1e,
    const float* __restrict__ fi_b2e,
    const float* __restrict__ fe_b1r, const float* __restrict__ fe_b2r,
    const float* __restrict__ fe_w1e, const float* __restrict__ fe_b1e,
    const float* __restrict__ fe_b2e,
    const unsigned short* __restrict__ q_inv, const unsigned short* __restrict__ k_inv,
    const unsigned short* __restrict__ q_ev, const unsigned short* __restrict__ k_ev,
    float* __restrict__ alpha_g)
{
    __shared__ unsigned short w2lds[16384];     // w2rT staged, 32KB, swizzled
    __shared__ unsigned short h1buf[TEB][140];  // h1 -> fw bf16 (280B rows)

    const int tid = threadIdx.x;
    const int lane = tid & 63;
    const int wv = tid >> 6;        // wave 0..3
    const int wb = wv * 16;         // wave's edge row base within 64-edge tile
    const int nchunk = gridDim.x >> 3;
    const int wgid = (blockIdx.x & 7) * nchunk + (blockIdx.x >> 3);
    const int e0 = wgid * (TEB * TPB_E);
    const int pass = blockIdx.y;    // 0 = fi, 1 = fe
    const int lrow = lane & 15;
    const int lk = lane >> 4;
    const int rj = (lane & 3) * 8;
    const int rrow = lane >> 2;     // he1 compute row (0..15)

    const float* b1r = pass ? fe_b1r : fi_b1r;
    const float* b2r = pass ? fe_b2r : fi_b2r;
    const float* w1e = pass ? fe_w1e : fi_w1e;
    const float* b1e = pass ? fe_b1e : fi_b1e;
    const float* b2e = pass ? fe_b2e : fi_b2e;
    const unsigned short* qtab = pass == 0 ? q_inv : q_ev;
    const unsigned short* ktab = pass == 0 ? k_inv : k_ev;
    // global weight tables, [col][k] layout, 8KB each (L1-resident after tile 0)
    const unsigned short* w1g  = wbf + pass * 24576;          // w1rT
    const unsigned short* w2eg = wbf + pass * 24576 + 20480;  // w2eT

    // ---- stage w2rT only (2048 chunks, swizzled) ----
    {
        const short8v* src = (const short8v*)(wbf + pass * 24576 + 4096);
        short8v* dst = (short8v*)w2lds;
        #pragma unroll
        for (int i = 0; i < 8; ++i) {
            const int c = tid + 256 * i;        // 16B-chunk index 0..2047
            const int col = c >> 4;
            const int slot = c & 15;
            dst[(c & ~15) | (slot ^ (col & 7))] = src[c];
        }
    }

    // ---- prologue: tile 0 pipeline state (indices + rbf A-frag only) ----
    int sC, rC;
    short8v rbC;     // A-fragment direct: row lrow, k-slice lk
    {
        const int ge = e0 + wb + lrow;
        sC = s_sid[ge]; rC = s_rid[ge];
        rbC = *(const short8v*)(rbf_s + (size_t)(e0 + wb + lrow) * 32 + lk * 8);
    }
    __syncthreads();   // weight LDS ready (single barrier; pipeline barrier-free)

    const int baddr = (((lane & 15) << 2) | (lane >> 4)) << 2;  // he1 transpose src

    #pragma unroll 1
    for (int t = 0; t < TPB_E; ++t) {
        const int tbase = e0 + t * TEB;

        // ---- issue current tile's dependent gathers (drain under MFMAs) ----
        const unsigned short* qb = qtab + (size_t)rC * 128 + lk * 32;
        const unsigned short* kb = ktab + (size_t)sC * 128 + lk * 32;
        const short8v pq0 = *(const short8v*)qb;
        const short8v pq1 = *(const short8v*)(qb + 8);
        const short8v pq2 = *(const short8v*)(qb + 16);
        const short8v pq3 = *(const short8v*)(qb + 24);
        const short8v pk0 = *(const short8v*)kb;
        const short8v pk1 = *(const short8v*)(kb + 8);
        const short8v pk2 = *(const short8v*)(kb + 16);
        const short8v pk3 = *(const short8v*)(kb + 24);

        // ---- current tile ev/cut: sequential streams, issued early/used late
        const float4 evC = *(const float4*)(evinv_s + (size_t)(tbase + wb + rrow) * 4);
        const float cC = cut_s[tbase + wb + lrow];

        // ---- issue next tile's independent loads (sequential) ----
        int sN = 0, rN = 0;
        short8v rbN;
        if (t + 1 < TPB_E) {
            const int gn = tbase + TEB + wb + lrow;
            sN = s_sid[gn]; rN = s_rid[gn];
            rbN = *(const short8v*)(rbf_s + (size_t)(tbase + TEB + wb + lrow) * 32 + lk * 8);
        }

        // ---- stage 1: h1 = silu(rbf @ w1r + b1r), 8 MFMAs (inline B-frag) ----
        {
            const short8v a1 = rbC;
            #pragma unroll
            for (int tt = 0; tt < 8; ++tt) {
                const int col = tt * 16 + lrow;
                const float b = b1r[col];
                f32x4 c; c[0] = b; c[1] = b; c[2] = b; c[3] = b;
                const short8v bv = *(const short8v*)(w1g + col * 32 + lk * 8);
                c = __builtin_amdgcn_mfma_f32_16x16x32_bf16(a1, bv, c, 0, 0, 0);
                #pragma unroll
                for (int rg = 0; rg < 4; ++rg)
                    h1buf[wb + lk * 4 + rg][col] = f2bt(silu_f(c[rg]));
            }
        }
        // ---- he1 = silu(evinv @ w1e + b1e), wave-local + bpermute transpose ----
        short8v ae;
        {
            const float v0 = evC.x, v1 = evC.y, v2 = evC.z, v3 = evC.w;
            short8v pk_;
            #pragma unroll
            for (int q = 0; q < 2; ++q) {
                const int j = rj + q * 4;
                const float4 bb = *(const float4*)(b1e + j);
                const float4 r0 = *(const float4*)(w1e + j);
                const float4 r1 = *(const float4*)(w1e + 32 + j);
                const float4 r2 = *(const float4*)(w1e + 64 + j);
                const float4 r3 = *(const float4*)(w1e + 96 + j);
                pk_[q * 4 + 0] = f2bt(silu_f(bb.x + v0 * r0.x + v1 * r1.x + v2 * r2.x + v3 * r3.x));
                pk_[q * 4 + 1] = f2bt(silu_f(bb.y + v0 * r0.y + v1 * r1.y + v2 * r2.y + v3 * r3.y));
                pk_[q * 4 + 2] = f2bt(silu_f(bb.z + v0 * r0.z + v1 * r1.z + v2 * r2.z + v3 * r3.z));
                pk_[q * 4 + 3] = f2bt(silu_f(bb.w + v0 * r0.w + v1 * r1.w + v2 * r2.w + v3 * r3.w));
            }
            // lane (lk,lrow) needs he1[row lrow][cols lk*8..+7] = the 4 dwords
            // of source lane (lrow*4 + lk); fixed pattern, verified in r30.
            union { short8v v; int i[4]; } u; u.v = pk_;
            union { int i[4]; short8v v; } o;
            o.i[0] = __builtin_amdgcn_ds_bpermute(baddr, u.i[0]);
            o.i[1] = __builtin_amdgcn_ds_bpermute(baddr, u.i[1]);
            o.i[2] = __builtin_amdgcn_ds_bpermute(baddr, u.i[2]);
            o.i[3] = __builtin_amdgcn_ds_bpermute(baddr, u.i[3]);
            ae = o.v;
        }

        // ---- stage 2: fw = h1 @ w2r + he1 @ w2e + biases, 40 MFMAs ----
        f32x4 acc[8];
        #pragma unroll
        for (int tt = 0; tt < 8; ++tt) {
            const int col = tt * 16 + lrow;
            const float b = b2r[col] + b2e[col];
            acc[tt][0] = b; acc[tt][1] = b; acc[tt][2] = b; acc[tt][3] = b;
        }
        #pragma unroll
        for (int ks = 0; ks < 4; ++ks) {
            const short8v av = *(const short8v*)&h1buf[wb + lrow][ks * 32 + lk * 8];
            const int slot = ks * 4 + lk;               // 16B slot within row
            #pragma unroll
            for (int tt = 0; tt < 8; ++tt) {
                const int col = tt * 16 + lrow;
                const short8v bv = *(const short8v*)&w2lds[
                    col * 128 + ((slot ^ (lrow & 7)) << 3)];
                acc[tt] = __builtin_amdgcn_mfma_f32_16x16x32_bf16(av, bv, acc[tt], 0, 0, 0);
            }
        }
        #pragma unroll
        for (int tt = 0; tt < 8; ++tt) {
            const int col = tt * 16 + lrow;
            const short8v bv = *(const short8v*)(w2eg + col * 32 + lk * 8);
            acc[tt] = __builtin_amdgcn_mfma_f32_16x16x32_bf16(ae, bv, acc[tt], 0, 0, 0);
        }

        // ---- write fw (bf16, truncating) back into h1buf ----
        #pragma unroll
        for (int tt = 0; tt < 8; ++tt) {
            const int col = tt * 16 + lrow;
            #pragma unroll
            for (int rg = 0; rg < 4; ++rg)
                h1buf[wb + lk * 4 + rg][col] = f2bt(acc[tt][rg]);
        }

        // ---- alpha: register q/k, fw from LDS, slot = sorted position ----
        const int slot = tbase + wb + lrow;
        if (pass == 0) {
            const int le = wb + lrow;
            #pragma unroll
            for (int it = 0; it < 2; ++it) {
                const int h = lk * 2 + it;          // 0..7
                const short8v f0 = *(const short8v*)&h1buf[le][h * 16];
                const short8v f1 = *(const short8v*)&h1buf[le][h * 16 + 8];
                const short8v qa = it ? pq2 : pq0;
                const short8v qc = it ? pq3 : pq1;
                const short8v ka = it ? pk2 : pk0;
                const short8v kc = it ? pk3 : pk1;
                float dot = 0.f;
                #pragma unroll
                for (int j = 0; j < 8; ++j)
                    dot += b2f(qa[j]) * b2f(ka[j]) * b2f(f0[j]);
                #pragma unroll
                for (int j = 0; j < 8; ++j)
                    dot += b2f(qc[j]) * b2f(kc[j]) * b2f(f1[j]);
                alpha_g[(size_t)slot * 12 + h] = dot * 0.25f * cC;
            }
        } else {
            const int le = wb + lrow;
            const int l = lk;                       // degree 0..3
            float dot = 0.f;
            #pragma unroll
            for (int c8 = 0; c8 < 4; ++c8) {
                const short8v fv = *(const short8v*)&h1buf[le][l * 32 + c8 * 8];
                const short8v qv = (c8 == 0) ? pq0 : (c8 == 1) ? pq1 : (c8 == 2) ? pq2 : pq3;
                const short8v kv = (c8 == 0) ? pk0 : (c8 == 1) ? pk1 : (c8 == 2) ? pk2 : pk3;
                #pragma unroll
                for (int j = 0; j < 8; ++j)
                    dot += b2f(qv[j]) * b2f(kv[j]) * b2f(fv[j]);
            }
            alpha_g[(size_t)slot * 12 + 8 + l] = dot * 0.17677669529663687f * cC;
        }

        // ---- rotate pipeline registers ----
        sC = sN; rC = rN; rbC = rbN;
    }
}

// ---------------------------------------------------------------------------
// Kernel 3: per-node gather + final 132x132 MLP (f32 int_w — r25 proven).
// ---------------------------------------------------------------------------
__global__ __launch_bounds__(256) void node_update(
    const float* __restrict__ inv, const float* __restrict__ ev,
    const unsigned short* __restrict__ v_inv,
    const unsigned short* __restrict__ sh_s,
    const float* __restrict__ alpha_g,
    const int* __restrict__ cnt, const int* __restrict__ off,
    const int* __restrict__ s_sid,
    const float* __restrict__ int_w, const float* __restrict__ int_b,
    float* __restrict__ out0, float* __restrict__ out1)
{
    const int tid = threadIdx.x;       // 0..255
    const int g16 = tid >> 4;          // gather group 0..15
    const int fl16 = tid & 15;         // lane in group
    const int f16 = fl16 * 8;          // feature base (8 feats, single head f16>>4)
    const int hsel = f16 >> 4;
    const int n = blockIdx.x;
    const int d = cnt[n];
    const int o = off[n];

    float accv[8];
    #pragma unroll
    for (int j = 0; j < 8; ++j) accv[j] = 0.f;
    float acce = 0.f;
    const int esel = 8 + degmap(fl16);

    for (int i = g16; i < d; i += 16) {
        const int p = o + i;
        const int sid = s_sid[p];
        const float a = alpha_g[(size_t)p * 12 + hsel];
        const short8v v = *(const short8v*)(v_inv + (size_t)sid * 128 + f16);
        #pragma unroll
        for (int j = 0; j < 8; ++j) accv[j] += a * b2f(v[j]);
        acce += alpha_g[(size_t)p * 12 + esel] * b2f(sh_s[(size_t)p * 16 + fl16]);
    }

    __shared__ float pv[16][128];
    __shared__ float pe[16][16];
    __shared__ float xin[132];
    __shared__ float ev1s[16];
    __shared__ float tcol[4];

    #pragma unroll
    for (int j = 0; j < 8; ++j) pv[g16][f16 + j] = accv[j];
    pe[g16][fl16] = acce;
    __syncthreads();

    // combine partials: threads 0..127 handle feature tid
    float iv = 0.f;
    if (tid < 128) {
        float s = 0.f;
        #pragma unroll
        for (int gg = 0; gg < 16; ++gg) s += pv[gg][tid];
        iv = inv[(size_t)n * 128 + tid] + s;
        xin[tid] = iv;
        if (tid < 16) {
            float se = 0.f;
            #pragma unroll
            for (int gg = 0; gg < 16; ++gg) se += pe[gg][tid];
            ev1s[tid] = ev[(size_t)n * 16 + tid] + se;
        }
    }
    __syncthreads();
    if (tid < 4) {
        const int st = (tid == 0) ? 0 : (tid == 1) ? 1 : (tid == 2) ? 4 : 9;
        const int en = (tid == 0) ? 1 : (tid == 1) ? 4 : (tid == 2) ? 9 : 16;
        float a = 0.f;
        for (int j = st; j < en; ++j) a += ev1s[j] * ev1s[j];
        xin[128 + tid] = a;
    }
    __syncthreads();

    // 132x132 matvec split 8-way over k (8 groups of 32 lanes)
    const int g = tid >> 5;
    const int fl = tid & 31;
    const int f = fl * 4;
    float4 macc; macc.x = 0.f; macc.y = 0.f; macc.z = 0.f; macc.w = 0.f;
    float macc2 = 0.f;
    const int k0 = g * 17;
    const int k1 = (k0 + 17 < 132) ? k0 + 17 : 132;
    for (int k = k0; k < k1; ++k) {
        const float xv = xin[k];
        const float4 w4 = *(const float4*)(int_w + k * 132 + f);
        macc.x += xv * w4.x; macc.y += xv * w4.y;
        macc.z += xv * w4.z; macc.w += xv * w4.w;
        if (fl < 4) macc2 += xv * int_w[k * 132 + 128 + fl];
    }
    __syncthreads();   // xin reads done; pv reuse
    *reinterpret_cast<float4*>(&pv[g][f]) = macc;
    if (fl < 4) pe[g][fl] = macc2;
    __syncthreads();

    if (tid < 128) {
        float s = int_b[tid];
        #pragma unroll
        for (int gg = 0; gg < 8; ++gg) s += pv[gg][tid];
        out0[(size_t)n * 128 + tid] = iv + s;
        if (tid < 4) {
            float s2 = int_b[128 + tid];
            #pragma unroll
            for (int gg = 0; gg < 8; ++gg) s2 += pe[gg][tid];
            tcol[tid] = s2;
        }
    }
    __syncthreads();
    if (tid < 16) out1[(size_t)n * 16 + tid] = ev1s[tid] * (1.0f + tcol[degmap(tid)]);
}

// ---------------------------------------------------------------------------
extern "C" void kernel_launch(void* const* d_in, const int* in_sizes, int n_in,
                              void* d_out, int out_size, void* d_ws, size_t ws_size,
                              hipStream_t stream) {
    const float* inv_features = (const float*)d_in[0];
    const float* ev_features  = (const float*)d_in[1];
    const float* rbf          = (const float*)d_in[2];
    const float* sh_vectors   = (const float*)d_in[3];
    const float* cutoffs      = (const float*)d_in[4];
    const int*   senders      = (const int*)d_in[5];
    const int*   receivers    = (const int*)d_in[6];
    const float* fi_rbf_w1 = (const float*)d_in[7];
    const float* fi_rbf_b1 = (const float*)d_in[8];
    const float* fi_rbf_w2 = (const float*)d_in[9];
    const float* fi_rbf_b2 = (const float*)d_in[10];
    const float* fi_ev_w1  = (const float*)d_in[11];
    const float* fi_ev_b1  = (const float*)d_in[12];
    const float* fi_ev_w2  = (const float*)d_in[13];
    const float* fi_ev_b2  = (const float*)d_in[14];
    const float* fe_rbf_w1 = (const float*)d_in[15];
    const float* fe_rbf_b1 = (const float*)d_in[16];
    const float* fe_rbf_w2 = (const float*)d_in[17];
    const float* fe_rbf_b2 = (const float*)d_in[18];
    const float* fe_ev_w1  = (const float*)d_in[19];
    const float* fe_ev_b1  = (const float*)d_in[20];
    const float* fe_ev_w2  = (const float*)d_in[21];
    const float* fe_ev_b2  = (const float*)d_in[22];
    const float* Wq_inv = (const float*)d_in[23];
    const float* Wk_inv = (const float*)d_in[24];
    const float* Wv_inv = (const float*)d_in[25];
    const float* Wq_ev  = (const float*)d_in[26];
    const float* Wk_ev  = (const float*)d_in[27];
    const float* int_w  = (const float*)d_in[28];
    const float* int_b  = (const float*)d_in[29];

    float* ws = (float*)d_ws;
    // bf16 tables: 5 x NN*128 ushort = NN*320 float-equivalents
    unsigned short* q_inv = (unsigned short*)ws;
    unsigned short* k_inv = q_inv + (size_t)NN * 128;
    unsigned short* v_inv = q_inv + (size_t)NN * 256;
    unsigned short* q_ev  = q_inv + (size_t)NN * 384;
    unsigned short* k_ev  = q_inv + (size_t)NN * 512;
    float* alpha_g = ws + (size_t)NN * 320;              // E*12 = NN*192 floats
    int*   cnt     = (int*)(ws + (size_t)NN * 512);      // NN
    int*   off     = cnt + NN;                            // NN
    int*   cursor  = cnt + 2 * NN;                        // NN
    int*   s_sid   = cnt + 3 * NN;                        // EE
    int*   s_rid   = s_sid + EE;                          // EE
    float* cut_s   = (float*)(s_rid + EE);                // EE
    float* evinv_s = cut_s + EE;                          // EE*4
    unsigned short* rbf_s = (unsigned short*)(evinv_s + (size_t)EE * 4);  // EE*32 ushorts
    unsigned short* sh_s  = rbf_s + (size_t)EE * 32;      // EE*16 ushorts
    unsigned short* wbf   = sh_s + (size_t)EE * 16;       // 49152 bf16

    hipMemsetAsync(cnt, 0, (size_t)3 * NN * sizeof(int), stream);

    fused_prep<<<1216, 256, 0, stream>>>(fi_rbf_w1, fi_rbf_w2, fi_ev_w2,
                                         fe_rbf_w1, fe_rbf_w2, fe_ev_w2, wbf,
                                         receivers, cnt);

    csr_scan<<<1, 256, 0, stream>>>(cnt, off);

    fused_fill<<<3072, 256, 0, stream>>>(receivers, senders, rbf, cutoffs, ev_features,
                                         sh_vectors, off, cursor, s_sid, s_rid,
                                         rbf_s, cut_s, evinv_s, sh_s,
                                         inv_features, Wq_inv, Wk_inv, Wv_inv,
                                         Wq_ev, Wk_ev,
                                         q_inv, k_inv, v_inv, q_ev, k_ev);

    dim3 egrid(EE / (TEB * TPB_E), 2);
    edge_kernel<<<egrid, 256, 0, stream>>>(
        rbf_s, cut_s, evinv_s, s_sid, s_rid, wbf,
        fi_rbf_b1, fi_rbf_b2, fi_ev_w1, fi_ev_b1, fi_ev_b2,
        fe_rbf_b1, fe_rbf_b2, fe_ev_w1, fe_ev_b1, fe_ev_b2,
        q_inv, k_inv, q_ev, k_ev, alpha_g);

    node_update<<<NN, 256, 0, stream>>>(inv_features, ev_features, v_inv, sh_s,
                                        alpha_g, cnt, off, s_sid,
                                        int_w, int_b,
                                        (float*)d_out, (float*)d_out + (size_t)NN * 128);
}

// Round 34
// 231.694 us; speedup vs baseline: 1.0572x; 1.0572x over previous
//
#include <hip/hip_runtime.h>
#include <math.h>

#define NN 16384
#define NRB 32
#define EE 262144
#define TEB 64          // edges per tile (4 waves x 16)
#define TPB_E 16        // tiles per block (software pipeline)

typedef __attribute__((ext_vector_type(8))) short short8v;   // 8 bf16
typedef __attribute__((ext_vector_type(4))) float f32x4;

__device__ __forceinline__ float silu_f(float x) {
    return x * __builtin_amdgcn_rcpf(1.0f + __expf(-x));
}
__device__ __forceinline__ int degmap(int j) { return (j == 0) ? 0 : (j < 4) ? 1 : (j < 9) ? 2 : 3; }
__device__ __forceinline__ unsigned short f2b(float f) {          // RNE (prep path)
    unsigned int u = __float_as_uint(f);
    unsigned int r = (u + 0x7FFFu + ((u >> 16) & 1u)) >> 16;
    return (unsigned short)r;
}
__device__ __forceinline__ unsigned short f2bt(float f) {         // truncate (hot path)
    return (unsigned short)(__float_as_uint(f) >> 16);
}
__device__ __forceinline__ float b2f(short s) {
    return __uint_as_float(((unsigned int)(unsigned short)s) << 16);
}

// ---------------------------------------------------------------------------
// FUSED dispatch 1: prep_weights (blocks 0..191) + csr_count (blocks 192..1215)
// ---------------------------------------------------------------------------
__global__ __launch_bounds__(256) void fused_prep(
    const float* __restrict__ fi_w1r, const float* __restrict__ fi_w2r,
    const float* __restrict__ fi_w2e,
    const float* __restrict__ fe_w1r, const float* __restrict__ fe_w2r,
    const float* __restrict__ fe_w2e,
    unsigned short* __restrict__ wbf,
    const int* __restrict__ recv,
    int* __restrict__ cnt)
{
    const int tid = threadIdx.x;
    if (blockIdx.x < 192) {
        const int id = blockIdx.x * 256 + tid;   // 49152 total
        if (id >= 2 * 24576) return;
        const int p = id / 24576;
        const int r = id % 24576;
        const float* w1r = p ? fe_w1r : fi_w1r;
        const float* w2r = p ? fe_w2r : fi_w2r;
        const float* w2e = p ? fe_w2e : fi_w2e;
        float v;
        if (r < 4096) {               // w1rT: c = r>>5, k = r&31
            v = w1r[(r & 31) * 128 + (r >> 5)];
        } else if (r < 20480) {       // w2rT: c = rr>>7, k = rr&127
            const int rr = r - 4096;
            v = w2r[(rr & 127) * 128 + (rr >> 7)];
        } else {                      // w2eT: c = rr>>5, k = rr&31
            const int rr = r - 20480;
            v = w2e[(rr & 31) * 128 + (rr >> 5)];
        }
        wbf[p * 24576 + r] = f2b(v);
    } else {
        const int e = (blockIdx.x - 192) * 256 + tid;
        if (e < EE) atomicAdd(&cnt[recv[e]], 1);
    }
}

// ---------------------------------------------------------------------------
// csr_scan (single block)
// ---------------------------------------------------------------------------
__global__ __launch_bounds__(256) void csr_scan(const int* __restrict__ cnt,
                                                int* __restrict__ off) {
    __shared__ int ps[256];
    const int t = threadIdx.x;
    const int base = t * 64;
    int s = 0;
    for (int i = 0; i < 64; ++i) s += cnt[base + i];
    ps[t] = s;
    __syncthreads();
    for (int dd = 1; dd < 256; dd <<= 1) {
        int v = 0;
        if (t >= dd) v = ps[t - dd];
        __syncthreads();
        ps[t] += v;
        __syncthreads();
    }
    int run = ps[t] - s;  // exclusive prefix
    for (int i = 0; i < 64; ++i) {
        off[base + i] = run;
        run += cnt[base + i];
    }
}

// ---------------------------------------------------------------------------
// FUSED dispatch 3: csr_fill (blocks 0..1023) + node_proj (blocks 1024..3071).
// ---------------------------------------------------------------------------
__global__ __launch_bounds__(256) void fused_fill(
    const int* __restrict__ recv,
    const int* __restrict__ send,
    const float* __restrict__ rbf,
    const float* __restrict__ cutoffs,
    const float* __restrict__ ev_feat,
    const float* __restrict__ sh,
    const int* __restrict__ off,
    int* __restrict__ cursor,
    int* __restrict__ s_sid,
    int* __restrict__ s_rid,
    unsigned short* __restrict__ rbf_s,
    float* __restrict__ cut_s,
    float* __restrict__ evinv_s,
    unsigned short* __restrict__ sh_s,
    const float* __restrict__ inv,
    const float* __restrict__ Wq_inv, const float* __restrict__ Wk_inv,
    const float* __restrict__ Wv_inv,
    const float* __restrict__ Wq_ev, const float* __restrict__ Wk_ev,
    unsigned short* __restrict__ q_inv, unsigned short* __restrict__ k_inv,
    unsigned short* __restrict__ v_inv,
    unsigned short* __restrict__ q_ev, unsigned short* __restrict__ k_ev)
{
    const int tid = threadIdx.x;
    if (blockIdx.x < 1024) {
        // ---------------- csr_fill ----------------
        const int e = blockIdx.x * 256 + tid;
        if (e < EE) {
            const int r = recv[e];
            const int s = send[e];
            const int p = off[r] + atomicAdd(&cursor[r], 1);
            s_sid[p] = s;
            s_rid[p] = r;
            cut_s[p] = cutoffs[e];
            const float* src = rbf + (size_t)e * 32;
            unsigned short* dst = rbf_s + (size_t)p * 32;
            #pragma unroll
            for (int c = 0; c < 4; ++c) {
                const float4 a = *(const float4*)(src + c * 8);
                const float4 b = *(const float4*)(src + c * 8 + 4);
                short8v pk;
                pk[0] = f2b(a.x); pk[1] = f2b(a.y); pk[2] = f2b(a.z); pk[3] = f2b(a.w);
                pk[4] = f2b(b.x); pk[5] = f2b(b.y); pk[6] = f2b(b.z); pk[7] = f2b(b.w);
                *(short8v*)(dst + c * 8) = pk;
            }
            const float* shp = sh + (size_t)e * 16;
            unsigned short* shd = sh_s + (size_t)p * 16;
            #pragma unroll
            for (int c = 0; c < 2; ++c) {
                const float4 a = *(const float4*)(shp + c * 8);
                const float4 b = *(const float4*)(shp + c * 8 + 4);
                short8v pk;
                pk[0] = f2b(a.x); pk[1] = f2b(a.y); pk[2] = f2b(a.z); pk[3] = f2b(a.w);
                pk[4] = f2b(b.x); pk[5] = f2b(b.y); pk[6] = f2b(b.z); pk[7] = f2b(b.w);
                *(short8v*)(shd + c * 8) = pk;
            }
            const float* es = ev_feat + (size_t)s * 16;
            const float* er = ev_feat + (size_t)r * 16;
            float df[16];
            #pragma unroll
            for (int j = 0; j < 16; j += 4) {
                const float4 a = *(const float4*)(es + j);
                const float4 b = *(const float4*)(er + j);
                df[j] = a.x - b.x; df[j + 1] = a.y - b.y;
                df[j + 2] = a.z - b.z; df[j + 3] = a.w - b.w;
            }
            float4 ev4;
            ev4.x = df[0] * df[0];
            ev4.y = df[1] * df[1] + df[2] * df[2] + df[3] * df[3];
            float a2 = 0.f;
            #pragma unroll
            for (int j = 4; j < 9; ++j) a2 += df[j] * df[j];
            ev4.z = a2;
            float a3 = 0.f;
            #pragma unroll
            for (int j = 9; j < 16; ++j) a3 += df[j] * df[j];
            ev4.w = a3;
            *(float4*)(evinv_s + (size_t)p * 4) = ev4;
        }
    } else {
        // ---------------- node_proj (2 nodes/iter x 4 iters) ----------------
        const int b = blockIdx.x - 1024;       // 0..2047
        const int t = tid & 127;
        const int half = tid >> 7;
        const int h = t >> 4, e = t & 15;
        const int l = t >> 5, e2 = t & 31;

        float wq[16], wk[16], wv[16];
        #pragma unroll
        for (int d = 0; d < 16; ++d) {
            wq[d] = Wq_inv[h * 256 + d * 16 + e];
            wk[d] = Wk_inv[h * 256 + d * 16 + e];
            wv[d] = Wv_inv[h * 256 + d * 16 + e];
        }
        float wqe[32], wke[32];
        #pragma unroll
        for (int d = 0; d < 32; ++d) {
            wqe[d] = Wq_ev[l * 1024 + d * 32 + e2];
            wke[d] = Wk_ev[l * 1024 + d * 32 + e2];
        }

        __shared__ float x[256];
        for (int nn = 0; nn < 4; ++nn) {
            const int n = b * 8 + nn * 2 + half;
            __syncthreads();
            x[half * 128 + t] = inv[(size_t)n * 128 + t];
            __syncthreads();
            float aq = 0.f, ak = 0.f, av = 0.f;
            #pragma unroll
            for (int d = 0; d < 16; ++d) {
                const float xv = x[half * 128 + h * 16 + d];
                aq += xv * wq[d]; ak += xv * wk[d]; av += xv * wv[d];
            }
            q_inv[(size_t)n * 128 + t] = f2b(aq);
            k_inv[(size_t)n * 128 + t] = f2b(ak);
            v_inv[(size_t)n * 128 + t] = f2b(av);
            float bq = 0.f, bk = 0.f;
            #pragma unroll
            for (int d = 0; d < 32; ++d) {
                const float xv = x[half * 128 + l * 32 + d];
                bq += xv * wqe[d]; bk += xv * wke[d];
            }
            q_ev[(size_t)n * 128 + t] = f2b(bq);
            k_ev[(size_t)n * 128 + t] = f2b(bk);
        }
    }
}

// ---------------------------------------------------------------------------
// Kernel 2: MFMA edge kernel (r32, best: 89.8us). w2rT in LDS (swizzled),
//   w1/w2e B-frags inline from global (L1-hot), direct rbf A-frags,
//   bpermute he1 transpose, full cross-tile prefetch pipeline {s,r,c,rb,ev}.
// ---------------------------------------------------------------------------
__global__ __launch_bounds__(256) void edge_kernel(
    const unsigned short* __restrict__ rbf_s,
    const float* __restrict__ cut_s,
    const float* __restrict__ evinv_s,
    const int* __restrict__ s_sid,
    const int* __restrict__ s_rid,
    const unsigned short* __restrict__ wbf,
    const float* __restrict__ fi_b1r, const float* __restrict__ fi_b2r,
    const float* __restrict__ fi_w1e, const float* __restrict__ fi_b1e,
    const float* __restrict__ fi_b2e,
    const float* __restrict__ fe_b1r, const float* __restrict__ fe_b2r,
    const float* __restrict__ fe_w1e, const float* __restrict__ fe_b1e,
    const float* __restrict__ fe_b2e,
    const unsigned short* __restrict__ q_inv, const unsigned short* __restrict__ k_inv,
    const unsigned short* __restrict__ q_ev, const unsigned short* __restrict__ k_ev,
    float* __restrict__ alpha_g)
{
    __shared__ unsigned short w2lds[16384];     // w2rT staged, 32KB, swizzled
    __shared__ unsigned short h1buf[TEB][140];  // h1 -> fw bf16 (280B rows)

    const int tid = threadIdx.x;
    const int lane = tid & 63;
    const int wv = tid >> 6;        // wave 0..3
    const int wb = wv * 16;         // wave's edge row base within 64-edge tile
    const int nchunk = gridDim.x >> 3;
    const int wgid = (blockIdx.x & 7) * nchunk + (blockIdx.x >> 3);
    const int e0 = wgid * (TEB * TPB_E);
    const int pass = blockIdx.y;    // 0 = fi, 1 = fe
    const int lrow = lane & 15;
    const int lk = lane >> 4;
    const int rj = (lane & 3) * 8;
    const int rrow = lane >> 2;     // he1 compute row (0..15)

    const float* b1r = pass ? fe_b1r : fi_b1r;
    const float* b2r = pass ? fe_b2r : fi_b2r;
    const float* w1e = pass ? fe_w1e : fi_w1e;
    const float* b1e = pass ? fe_b1e : fi_b1e;
    const float* b2e = pass ? fe_b2e : fi_b2e;
    const unsigned short* qtab = pass == 0 ? q_inv : q_ev;
    const unsigned short* ktab = pass == 0 ? k_inv : k_ev;
    // global weight tables, [col][k] layout, 8KB each (L1-resident after tile 0)
    const unsigned short* w1g  = wbf + pass * 24576;          // w1rT
    const unsigned short* w2eg = wbf + pass * 24576 + 20480;  // w2eT

    // ---- stage w2rT only (2048 chunks, swizzled) ----
    {
        const short8v* src = (const short8v*)(wbf + pass * 24576 + 4096);
        short8v* dst = (short8v*)w2lds;
        #pragma unroll
        for (int i = 0; i < 8; ++i) {
            const int c = tid + 256 * i;        // 16B-chunk index 0..2047
            const int col = c >> 4;
            const int slot = c & 15;
            dst[(c & ~15) | (slot ^ (col & 7))] = src[c];
        }
    }

    // ---- prologue: tile 0 loads (all sequential in sorted order) ----
    int sC, rC;
    float cC;
    short8v rbC;     // A-fragment direct: row lrow, k-slice lk
    float4 evC;      // evinv row rrow (4-lane redundant, same cacheline)
    {
        const int ge = e0 + wb + lrow;
        sC = s_sid[ge]; rC = s_rid[ge]; cC = cut_s[ge];
        rbC = *(const short8v*)(rbf_s + (size_t)(e0 + wb + lrow) * 32 + lk * 8);
        evC = *(const float4*)(evinv_s + (size_t)(e0 + wb + rrow) * 4);
    }
    __syncthreads();   // weight LDS ready (single barrier; pipeline barrier-free)

    const int baddr = (((lane & 15) << 2) | (lane >> 4)) << 2;  // he1 transpose src

    #pragma unroll 1
    for (int t = 0; t < TPB_E; ++t) {
        const int tbase = e0 + t * TEB;

        // ---- issue current tile's dependent gathers (drain under MFMAs) ----
        const unsigned short* qb = qtab + (size_t)rC * 128 + lk * 32;
        const unsigned short* kb = ktab + (size_t)sC * 128 + lk * 32;
        const short8v pq0 = *(const short8v*)qb;
        const short8v pq1 = *(const short8v*)(qb + 8);
        const short8v pq2 = *(const short8v*)(qb + 16);
        const short8v pq3 = *(const short8v*)(qb + 24);
        const short8v pk0 = *(const short8v*)kb;
        const short8v pk1 = *(const short8v*)(kb + 8);
        const short8v pk2 = *(const short8v*)(kb + 16);
        const short8v pk3 = *(const short8v*)(kb + 24);

        // ---- issue next tile's independent loads (sequential) ----
        int sN = 0, rN = 0;
        float cN = 0.f;
        short8v rbN;
        float4 evN;
        if (t + 1 < TPB_E) {
            const int gn = tbase + TEB + wb + lrow;
            sN = s_sid[gn]; rN = s_rid[gn]; cN = cut_s[gn];
            rbN = *(const short8v*)(rbf_s + (size_t)(tbase + TEB + wb + lrow) * 32 + lk * 8);
            evN = *(const float4*)(evinv_s + (size_t)(tbase + TEB + wb + rrow) * 4);
        }

        // ---- stage 1: h1 = silu(rbf @ w1r + b1r), 8 MFMAs (inline B-frag) ----
        {
            const short8v a1 = rbC;
            #pragma unroll
            for (int tt = 0; tt < 8; ++tt) {
                const int col = tt * 16 + lrow;
                const float b = b1r[col];
                f32x4 c; c[0] = b; c[1] = b; c[2] = b; c[3] = b;
                const short8v bv = *(const short8v*)(w1g + col * 32 + lk * 8);
                c = __builtin_amdgcn_mfma_f32_16x16x32_bf16(a1, bv, c, 0, 0, 0);
                #pragma unroll
                for (int rg = 0; rg < 4; ++rg)
                    h1buf[wb + lk * 4 + rg][col] = f2bt(silu_f(c[rg]));
            }
        }
        // ---- he1 = silu(evinv @ w1e + b1e), wave-local + bpermute transpose ----
        short8v ae;
        {
            const float v0 = evC.x, v1 = evC.y, v2 = evC.z, v3 = evC.w;
            short8v pk_;
            #pragma unroll
            for (int q = 0; q < 2; ++q) {
                const int j = rj + q * 4;
                const float4 bb = *(const float4*)(b1e + j);
                const float4 r0 = *(const float4*)(w1e + j);
                const float4 r1 = *(const float4*)(w1e + 32 + j);
                const float4 r2 = *(const float4*)(w1e + 64 + j);
                const float4 r3 = *(const float4*)(w1e + 96 + j);
                pk_[q * 4 + 0] = f2bt(silu_f(bb.x + v0 * r0.x + v1 * r1.x + v2 * r2.x + v3 * r3.x));
                pk_[q * 4 + 1] = f2bt(silu_f(bb.y + v0 * r0.y + v1 * r1.y + v2 * r2.y + v3 * r3.y));
                pk_[q * 4 + 2] = f2bt(silu_f(bb.z + v0 * r0.z + v1 * r1.z + v2 * r2.z + v3 * r3.z));
                pk_[q * 4 + 3] = f2bt(silu_f(bb.w + v0 * r0.w + v1 * r1.w + v2 * r2.w + v3 * r3.w));
            }
            // lane (lk,lrow) needs he1[row lrow][cols lk*8..+7] = the 4 dwords
            // of source lane (lrow*4 + lk); fixed pattern, verified in r30.
            union { short8v v; int i[4]; } u; u.v = pk_;
            union { int i[4]; short8v v; } o;
            o.i[0] = __builtin_amdgcn_ds_bpermute(baddr, u.i[0]);
            o.i[1] = __builtin_amdgcn_ds_bpermute(baddr, u.i[1]);
            o.i[2] = __builtin_amdgcn_ds_bpermute(baddr, u.i[2]);
            o.i[3] = __builtin_amdgcn_ds_bpermute(baddr, u.i[3]);
            ae = o.v;
        }

        // ---- stage 2: fw = h1 @ w2r + he1 @ w2e + biases, 40 MFMAs ----
        f32x4 acc[8];
        #pragma unroll
        for (int tt = 0; tt < 8; ++tt) {
            const int col = tt * 16 + lrow;
            const float b = b2r[col] + b2e[col];
            acc[tt][0] = b; acc[tt][1] = b; acc[tt][2] = b; acc[tt][3] = b;
        }
        #pragma unroll
        for (int ks = 0; ks < 4; ++ks) {
            const short8v av = *(const short8v*)&h1buf[wb + lrow][ks * 32 + lk * 8];
            const int slot = ks * 4 + lk;               // 16B slot within row
            #pragma unroll
            for (int tt = 0; tt < 8; ++tt) {
                const int col = tt * 16 + lrow;
                const short8v bv = *(const short8v*)&w2lds[
                    col * 128 + ((slot ^ (lrow & 7)) << 3)];
                acc[tt] = __builtin_amdgcn_mfma_f32_16x16x32_bf16(av, bv, acc[tt], 0, 0, 0);
            }
        }
        #pragma unroll
        for (int tt = 0; tt < 8; ++tt) {
            const int col = tt * 16 + lrow;
            const short8v bv = *(const short8v*)(w2eg + col * 32 + lk * 8);
            acc[tt] = __builtin_amdgcn_mfma_f32_16x16x32_bf16(ae, bv, acc[tt], 0, 0, 0);
        }

        // ---- write fw (bf16, truncating) back into h1buf ----
        #pragma unroll
        for (int tt = 0; tt < 8; ++tt) {
            const int col = tt * 16 + lrow;
            #pragma unroll
            for (int rg = 0; rg < 4; ++rg)
                h1buf[wb + lk * 4 + rg][col] = f2bt(acc[tt][rg]);
        }

        // ---- alpha: register q/k, fw from LDS, slot = sorted position ----
        const int slot = tbase + wb + lrow;
        if (pass == 0) {
            const int le = wb + lrow;
            #pragma unroll
            for (int it = 0; it < 2; ++it) {
                const int h = lk * 2 + it;          // 0..7
                const short8v f0 = *(const short8v*)&h1buf[le][h * 16];
                const short8v f1 = *(const short8v*)&h1buf[le][h * 16 + 8];
                const short8v qa = it ? pq2 : pq0;
                const short8v qc = it ? pq3 : pq1;
                const short8v ka = it ? pk2 : pk0;
                const short8v kc = it ? pk3 : pk1;
                float dot = 0.f;
                #pragma unroll
                for (int j = 0; j < 8; ++j)
                    dot += b2f(qa[j]) * b2f(ka[j]) * b2f(f0[j]);
                #pragma unroll
                for (int j = 0; j < 8; ++j)
                    dot += b2f(qc[j]) * b2f(kc[j]) * b2f(f1[j]);
                alpha_g[(size_t)slot * 12 + h] = dot * 0.25f * cC;
            }
        } else {
            const int le = wb + lrow;
            const int l = lk;                       // degree 0..3
            float dot = 0.f;
            #pragma unroll
            for (int c8 = 0; c8 < 4; ++c8) {
                const short8v fv = *(const short8v*)&h1buf[le][l * 32 + c8 * 8];
                const short8v qv = (c8 == 0) ? pq0 : (c8 == 1) ? pq1 : (c8 == 2) ? pq2 : pq3;
                const short8v kv = (c8 == 0) ? pk0 : (c8 == 1) ? pk1 : (c8 == 2) ? pk2 : pk3;
                #pragma unroll
                for (int j = 0; j < 8; ++j)
                    dot += b2f(qv[j]) * b2f(kv[j]) * b2f(fv[j]);
            }
            alpha_g[(size_t)slot * 12 + 8 + l] = dot * 0.17677669529663687f * cC;
        }

        // ---- rotate pipeline registers ----
        sC = sN; rC = rN; cC = cN; rbC = rbN; evC = evN;
    }
}

// ---------------------------------------------------------------------------
// Kernel 3: per-node gather + final 132x132 MLP (f32 int_w — r25 proven).
// ---------------------------------------------------------------------------
__global__ __launch_bounds__(256) void node_update(
    const float* __restrict__ inv, const float* __restrict__ ev,
    const unsigned short* __restrict__ v_inv,
    const unsigned short* __restrict__ sh_s,
    const float* __restrict__ alpha_g,
    const int* __restrict__ cnt, const int* __restrict__ off,
    const int* __restrict__ s_sid,
    const float* __restrict__ int_w, const float* __restrict__ int_b,
    float* __restrict__ out0, float* __restrict__ out1)
{
    const int tid = threadIdx.x;       // 0..255
    const int g16 = tid >> 4;          // gather group 0..15
    const int fl16 = tid & 15;         // lane in group
    const int f16 = fl16 * 8;          // feature base (8 feats, single head f16>>4)
    const int hsel = f16 >> 4;
    const int n = blockIdx.x;
    const int d = cnt[n];
    const int o = off[n];

    float accv[8];
    #pragma unroll
    for (int j = 0; j < 8; ++j) accv[j] = 0.f;
    float acce = 0.f;
    const int esel = 8 + degmap(fl16);

    for (int i = g16; i < d; i += 16) {
        const int p = o + i;
        const int sid = s_sid[p];
        const float a = alpha_g[(size_t)p * 12 + hsel];
        const short8v v = *(const short8v*)(v_inv + (size_t)sid * 128 + f16);
        #pragma unroll
        for (int j = 0; j < 8; ++j) accv[j] += a * b2f(v[j]);
        acce += alpha_g[(size_t)p * 12 + esel] * b2f(sh_s[(size_t)p * 16 + fl16]);
    }

    __shared__ float pv[16][128];
    __shared__ float pe[16][16];
    __shared__ float xin[132];
    __shared__ float ev1s[16];
    __shared__ float tcol[4];

    #pragma unroll
    for (int j = 0; j < 8; ++j) pv[g16][f16 + j] = accv[j];
    pe[g16][fl16] = acce;
    __syncthreads();

    // combine partials: threads 0..127 handle feature tid
    float iv = 0.f;
    if (tid < 128) {
        float s = 0.f;
        #pragma unroll
        for (int gg = 0; gg < 16; ++gg) s += pv[gg][tid];
        iv = inv[(size_t)n * 128 + tid] + s;
        xin[tid] = iv;
        if (tid < 16) {
            float se = 0.f;
            #pragma unroll
            for (int gg = 0; gg < 16; ++gg) se += pe[gg][tid];
            ev1s[tid] = ev[(size_t)n * 16 + tid] + se;
        }
    }
    __syncthreads();
    if (tid < 4) {
        const int st = (tid == 0) ? 0 : (tid == 1) ? 1 : (tid == 2) ? 4 : 9;
        const int en = (tid == 0) ? 1 : (tid == 1) ? 4 : (tid == 2) ? 9 : 16;
        float a = 0.f;
        for (int j = st; j < en; ++j) a += ev1s[j] * ev1s[j];
        xin[128 + tid] = a;
    }
    __syncthreads();

    // 132x132 matvec split 8-way over k (8 groups of 32 lanes)
    const int g = tid >> 5;
    const int fl = tid & 31;
    const int f = fl * 4;
    float4 macc; macc.x = 0.f; macc.y = 0.f; macc.z = 0.f; macc.w = 0.f;
    float macc2 = 0.f;
    const int k0 = g * 17;
    const int k1 = (k0 + 17 < 132) ? k0 + 17 : 132;
    for (int k = k0; k < k1; ++k) {
        const float xv = xin[k];
        const float4 w4 = *(const float4*)(int_w + k * 132 + f);
        macc.x += xv * w4.x; macc.y += xv * w4.y;
        macc.z += xv * w4.z; macc.w += xv * w4.w;
        if (fl < 4) macc2 += xv * int_w[k * 132 + 128 + fl];
    }
    __syncthreads();   // xin reads done; pv reuse
    *reinterpret_cast<float4*>(&pv[g][f]) = macc;
    if (fl < 4) pe[g][fl] = macc2;
    __syncthreads();

    if (tid < 128) {
        float s = int_b[tid];
        #pragma unroll
        for (int gg = 0; gg < 8; ++gg) s += pv[gg][tid];
        out0[(size_t)n * 128 + tid] = iv + s;
        if (tid < 4) {
            float s2 = int_b[128 + tid];
            #pragma unroll
            for (int gg = 0; gg < 8; ++gg) s2 += pe[gg][tid];
            tcol[tid] = s2;
        }
    }
    __syncthreads();
    if (tid < 16) out1[(size_t)n * 16 + tid] = ev1s[tid] * (1.0f + tcol[degmap(tid)]);
}

// ---------------------------------------------------------------------------
extern "C" void kernel_launch(void* const* d_in, const int* in_sizes, int n_in,
                              void* d_out, int out_size, void* d_ws, size_t ws_size,
                              hipStream_t stream) {
    const float* inv_features = (const float*)d_in[0];
    const float* ev_features  = (const float*)d_in[1];
    const float* rbf          = (const float*)d_in[2];
    const float* sh_vectors   = (const float*)d_in[3];
    const float* cutoffs      = (const float*)d_in[4];
    const int*   senders      = (const int*)d_in[5];
    const int*   receivers    = (const int*)d_in[6];
    const float* fi_rbf_w1 = (const float*)d_in[7];
    const float* fi_rbf_b1 = (const float*)d_in[8];
    const float* fi_rbf_w2 = (const float*)d_in[9];
    const float* fi_rbf_b2 = (const float*)d_in[10];
    const float* fi_ev_w1  = (const float*)d_in[11];
    const float* fi_ev_b1  = (const float*)d_in[12];
    const float* fi_ev_w2  = (const float*)d_in[13];
    const float* fi_ev_b2  = (const float*)d_in[14];
    const float* fe_rbf_w1 = (const float*)d_in[15];
    const float* fe_rbf_b1 = (const float*)d_in[16];
    const float* fe_rbf_w2 = (const float*)d_in[17];
    const float* fe_rbf_b2 = (const float*)d_in[18];
    const float* fe_ev_w1  = (const float*)d_in[19];
    const float* fe_ev_b1  = (const float*)d_in[20];
    const float* fe_ev_w2  = (const float*)d_in[21];
    const float* fe_ev_b2  = (const float*)d_in[22];
    const float* Wq_inv = (const float*)d_in[23];
    const float* Wk_inv = (const float*)d_in[24];
    const float* Wv_inv = (const float*)d_in[25];
    const float* Wq_ev  = (const float*)d_in[26];
    const float* Wk_ev  = (const float*)d_in[27];
    const float* int_w  = (const float*)d_in[28];
    const float* int_b  = (const float*)d_in[29];

    float* ws = (float*)d_ws;
    // bf16 tables: 5 x NN*128 ushort = NN*320 float-equivalents
    unsigned short* q_inv = (unsigned short*)ws;
    unsigned short* k_inv = q_inv + (size_t)NN * 128;
    unsigned short* v_inv = q_inv + (size_t)NN * 256;
    unsigned short* q_ev  = q_inv + (size_t)NN * 384;
    unsigned short* k_ev  = q_inv + (size_t)NN * 512;
    float* alpha_g = ws + (size_t)NN * 320;              // E*12 = NN*192 floats
    int*   cnt     = (int*)(ws + (size_t)NN * 512);      // NN
    int*   off     = cnt + NN;                            // NN
    int*   cursor  = cnt + 2 * NN;                        // NN
    int*   s_sid   = cnt + 3 * NN;                        // EE
    int*   s_rid   = s_sid + EE;                          // EE
    float* cut_s   = (float*)(s_rid + EE);                // EE
    float* evinv_s = cut_s + EE;                          // EE*4
    unsigned short* rbf_s = (unsigned short*)(evinv_s + (size_t)EE * 4);  // EE*32 ushorts
    unsigned short* sh_s  = rbf_s + (size_t)EE * 32;      // EE*16 ushorts
    unsigned short* wbf   = sh_s + (size_t)EE * 16;       // 49152 bf16

    hipMemsetAsync(cnt, 0, (size_t)3 * NN * sizeof(int), stream);

    fused_prep<<<1216, 256, 0, stream>>>(fi_rbf_w1, fi_rbf_w2, fi_ev_w2,
                                         fe_rbf_w1, fe_rbf_w2, fe_ev_w2, wbf,
                                         receivers, cnt);

    csr_scan<<<1, 256, 0, stream>>>(cnt, off);

    fused_fill<<<3072, 256, 0, stream>>>(receivers, senders, rbf, cutoffs, ev_features,
                                         sh_vectors, off, cursor, s_sid, s_rid,
                                         rbf_s, cut_s, evinv_s, sh_s,
                                         inv_features, Wq_inv, Wk_inv, Wv_inv,
                                         Wq_ev, Wk_ev,
                                         q_inv, k_inv, v_inv, q_ev, k_ev);

    dim3 egrid(EE / (TEB * TPB_E), 2);
    edge_kernel<<<egrid, 256, 0, stream>>>(
        rbf_s, cut_s, evinv_s, s_sid, s_rid, wbf,
        fi_rbf_b1, fi_rbf_b2, fi_ev_w1, fi_ev_b1, fi_ev_b2,
        fe_rbf_b1, fe_rbf_b2, fe_ev_w1, fe_ev_b1, fe_ev_b2,
        q_inv, k_inv, q_ev, k_ev, alpha_g);

    node_update<<<NN, 256, 0, stream>>>(inv_features, ev_features, v_inv, sh_s,
                                        alpha_g, cnt, off, s_sid,
                                        int_w, int_b,
                                        (float*)d_out, (float*)d_out + (size_t)NN * 128);
}